// Round 5
// baseline (247.002 us; speedup 1.0000x reference)
//
#include <hip/hip_runtime.h>
#include <stdint.h>

#define NTOK 16384   // B*S = 4*4096
#define DIN 512
#define DOUT 512
#define KE 8
#define BM 128
#define BN 128
#define BK 64

#define GATE_BLOCKS 2048           // 8 tokens/block
#define WCONV_BLOCKS 1024          // 2M elements / (256*8)

typedef unsigned short u16;
typedef u16 u16x8 __attribute__((ext_vector_type(8)));
typedef __bf16 bf16x8 __attribute__((ext_vector_type(8)));
typedef float f32x4 __attribute__((ext_vector_type(4)));

__device__ __forceinline__ u16 f2bf(float f) {
  union { float f; unsigned u; } v; v.f = f;
  unsigned r = v.u + 0x7FFFu + ((v.u >> 16) & 1u);   // RNE; inputs are finite
  return (u16)(r >> 16);
}

// async global->LDS, 16B per lane; LDS dest is wave-uniform base + lane*16
#define GLOAD_LDS16(gp, lp)                                              \
  __builtin_amdgcn_global_load_lds(                                     \
      (__attribute__((address_space(1))) void*)(gp),                    \
      (__attribute__((address_space(3))) void*)(lp), 16, 0, 0)

// ---------------------------------------------------------------------------
// Kernel 1 (merged prologue):
//  blocks [0, GATE_BLOCKS): gating softmax + x fp32->bf16 cast (8 tok/block)
//  blocks [GATE_BLOCKS, +WCONV_BLOCKS): expert-weight fp32->bf16 cast
// Coeffs written TRANSPOSED: coeffsT[e][tok]  (so GEMM folds load float4).
// ---------------------------------------------------------------------------
__global__ __launch_bounds__(256) void prologue_kernel(
    const float* __restrict__ x, const float* __restrict__ mw,
    const float* __restrict__ mb, const float* __restrict__ ew,
    u16* __restrict__ xbf, u16* __restrict__ wbf, float* __restrict__ coeffsT) {
  const int tid = threadIdx.x;

  if (blockIdx.x >= GATE_BLOCKS) {
    // ---- weight cast: 8 elements/thread ----
    const size_t i =
        ((size_t)(blockIdx.x - GATE_BLOCKS) * 256 + tid) * 8;
    const float4 a = *(const float4*)&ew[i];
    const float4 b = *(const float4*)&ew[i + 4];
    u16x8 p;
    p[0] = f2bf(a.x); p[1] = f2bf(a.y); p[2] = f2bf(a.z); p[3] = f2bf(a.w);
    p[4] = f2bf(b.x); p[5] = f2bf(b.y); p[6] = f2bf(b.z); p[7] = f2bf(b.w);
    *(u16x8*)&wbf[i] = p;
    return;
  }

  // ---- gating + x cast ----
  __shared__ __align__(16) float mwS[KE * DIN];   // 16 KB
  const int wave = tid >> 6, lane = tid & 63;

#pragma unroll
  for (int i = 0; i < 4; ++i) {
    const int idx = (tid + i * 256) * 4;
    *(float4*)&mwS[idx] = *(const float4*)&mw[idx];
  }
  float mbr[KE];
#pragma unroll
  for (int k = 0; k < KE; ++k) mbr[k] = mb[k];
  __syncthreads();

#pragma unroll
  for (int t = 0; t < 2; ++t) {
    const int tok = blockIdx.x * 8 + wave * 2 + t;
    const float* xr = x + (size_t)tok * DIN + lane * 8;
    const float4 xa = *(const float4*)xr;
    const float4 xb = *(const float4*)(xr + 4);

    u16x8 p;
    p[0] = f2bf(xa.x); p[1] = f2bf(xa.y); p[2] = f2bf(xa.z); p[3] = f2bf(xa.w);
    p[4] = f2bf(xb.x); p[5] = f2bf(xb.y); p[6] = f2bf(xb.z); p[7] = f2bf(xb.w);
    *(u16x8*)(xbf + (size_t)tok * DIN + lane * 8) = p;

    float lg[KE];
#pragma unroll
    for (int k = 0; k < KE; ++k) {
      const float* wr = &mwS[k * DIN + lane * 8];
      const float4 w0 = *(const float4*)wr;
      const float4 w1 = *(const float4*)(wr + 4);
      lg[k] = xa.x * w0.x + xa.y * w0.y + xa.z * w0.z + xa.w * w0.w +
              xb.x * w1.x + xb.y * w1.y + xb.z * w1.z + xb.w * w1.w;
    }
#pragma unroll
    for (int off = 32; off; off >>= 1)
#pragma unroll
      for (int k = 0; k < KE; ++k) lg[k] += __shfl_xor(lg[k], off);

#pragma unroll
    for (int k = 0; k < KE; ++k) lg[k] += mbr[k];
    float mx = lg[0];
#pragma unroll
    for (int k = 1; k < KE; ++k) mx = fmaxf(mx, lg[k]);
    float s = 0.f;
#pragma unroll
    for (int k = 0; k < KE; ++k) { lg[k] = __expf(lg[k] - mx); s += lg[k]; }
    const float inv = 1.f / s;
    if (lane == 0) {
#pragma unroll
      for (int k = 0; k < KE; ++k) coeffsT[(size_t)k * NTOK + tok] = lg[k] * inv;
    }
  }
}

// ---------------------------------------------------------------------------
// Kernel 2: main MoE GEMM. BM=BN=128, BK=64, double-buffered LDS (64 KB),
// single barrier per K-iter: stage(t+1)->buf^1 issued BEFORE compute(t), so
// the barrier's vmcnt(0) drain overlaps ~1241 cyc of MFMA.
// - __launch_bounds__(256,1): reg budget 512 -> acc(64)+part(64)+frags(32)
//   fit WITHOUT spill (R3's 128-tile failure was compiler capping at 128
//   regs under (256,2) and spilling acc -> 255 MB scratch traffic).
// - XCD swizzle (R2/R4-verified): XCD b&7 owns 16 contiguous m-blocks.
// - XOR-swizzled LDS (R4-verified conflict-free): slot s of row r holds
//   global chunk s^(r&7).
// - coeffs read directly from L2 (transposed layout), bias in epilogue.
// ---------------------------------------------------------------------------
__global__ __launch_bounds__(256, 1) void moe_gemm_kernel(
    const u16* __restrict__ xbf, const u16* __restrict__ wbf,
    const float* __restrict__ coeffsT, const float* __restrict__ ebias,
    float* __restrict__ out) {
  __shared__ __align__(16) u16 As[2][BM * BK];   // 2 x 16 KB
  __shared__ __align__(16) u16 Bs[2][BN * BK];   // 2 x 16 KB

  const int tid = threadIdx.x;
  const int wave = tid >> 6, lane = tid & 63;

  // XCD swizzle: b&7 = xcd, s = intra-XCD sequence (all 64 co-resident).
  const int b = blockIdx.x;
  const int xcd = b & 7, s = b >> 3;
  const int m0 = (xcd * 16 + (s & 15)) * BM;
  const int n0 = (s >> 4) * BN;

  const int wm = (wave >> 1) * 64;   // wave's row offset: {0,64}
  const int wn = (wave & 1) * 64;    // wave's col offset: {0,64}

  // staging: chunk ci = wave*4+j covers tile rows ci*8..ci*8+7 (8 rows x 64
  // cols = 1 KB per GLOAD set). lane -> row lrow; SOURCE col chunk XOR-
  // swizzled so LDS slot s of row r = global chunk s^(r&7).
  const int lrow = lane >> 3;
  const int scol = ((lane & 7) ^ lrow) * 8;
  const u16* aBase = xbf + (size_t)(m0 + wave * 32 + lrow) * DIN + scol;
  const u16* bBase0 = wbf + (size_t)(n0 + wave * 32 + lrow) * DIN + scol;

  const int frow = lane & 15;
  const int fsel = lane >> 4;
  const int fxor = lane & 7;
  const int quad = lane >> 4;

  f32x4 acc[4][4] = {};
  f32x4 part[4][4] = {};

  // ---- stage(t, buf): t = e*8 + kt ----
#define STAGE(T, BUF)                                                         \
  do {                                                                        \
    const int kt_ = (T) & 7, e_ = (T) >> 3;                                   \
    const size_t koff_ = (size_t)kt_ * 64;                                    \
    const u16* bB_ = bBase0 + (size_t)e_ * (DOUT * DIN) + koff_;              \
    const u16* aB_ = aBase + koff_;                                           \
    _Pragma("unroll")                                                         \
    for (int j = 0; j < 4; ++j) {                                             \
      GLOAD_LDS16(aB_ + (size_t)(j * 8) * DIN, &As[BUF][(wave * 4 + j) * 512]); \
      GLOAD_LDS16(bB_ + (size_t)(j * 8) * DIN, &Bs[BUF][(wave * 4 + j) * 512]); \
    }                                                                         \
  } while (0)

  STAGE(0, 0);
  __syncthreads();

  for (int t = 0; t < 64; ++t) {
    const int buf = t & 1;
    if (t < 63) STAGE(t + 1, buf ^ 1);

#pragma unroll
    for (int ks = 0; ks < 2; ++ks) {
      const int slot = (ks * 4 + fsel) ^ fxor;   // pure lane fn (rows mult 8)
      bf16x8 af[4], bfv[4];
#pragma unroll
      for (int mi = 0; mi < 4; ++mi)
        af[mi] = *(const bf16x8*)&As[buf][(wm + mi * 16 + frow) * BK + slot * 8];
#pragma unroll
      for (int ni = 0; ni < 4; ++ni)
        bfv[ni] = *(const bf16x8*)&Bs[buf][(wn + ni * 16 + frow) * BK + slot * 8];
#pragma unroll
      for (int mi = 0; mi < 4; ++mi)
#pragma unroll
        for (int ni = 0; ni < 4; ++ni)
          part[mi][ni] = __builtin_amdgcn_mfma_f32_16x16x32_bf16(
              af[mi], bfv[ni], part[mi][ni], 0, 0, 0);
    }

    if ((t & 7) == 7) {
      // fold expert partial into acc, scaled by c[row, e] (fp32, from L2)
      // C/D layout (m89/m91): col = lane&15, row = quad*4 + reg
      const int e = t >> 3;
      const float* cT = coeffsT + (size_t)e * NTOK + m0;
#pragma unroll
      for (int mi = 0; mi < 4; ++mi) {
        const float4 c4 = *(const float4*)&cT[wm + mi * 16 + quad * 4];
#pragma unroll
        for (int ni = 0; ni < 4; ++ni) {
          acc[mi][ni][0] += c4.x * part[mi][ni][0];
          acc[mi][ni][1] += c4.y * part[mi][ni][1];
          acc[mi][ni][2] += c4.z * part[mi][ni][2];
          acc[mi][ni][3] += c4.w * part[mi][ni][3];
          part[mi][ni] = (f32x4)(0.f);
        }
      }
    }

    if (t < 63) __syncthreads();   // drains stage(t+1); syncs buffer swap
  }

  // epilogue: rank-8 bias update + store (coeffs/bias straight from L2)
  float bcol[4][KE];
#pragma unroll
  for (int ni = 0; ni < 4; ++ni) {
    const int col = wn + ni * 16 + frow;
#pragma unroll
    for (int k = 0; k < KE; ++k) bcol[ni][k] = ebias[k * DOUT + n0 + col];
  }
#pragma unroll
  for (int mi = 0; mi < 4; ++mi) {
    const int rb = wm + mi * 16 + quad * 4;
#pragma unroll
    for (int j = 0; j < 4; ++j) {
      const int row = rb + j;
      float cr[KE];
#pragma unroll
      for (int k = 0; k < KE; ++k)
        cr[k] = coeffsT[(size_t)k * NTOK + m0 + row];
#pragma unroll
      for (int ni = 0; ni < 4; ++ni) {
        float bias = 0.f;
#pragma unroll
        for (int k = 0; k < KE; ++k) bias += cr[k] * bcol[ni][k];
        const int col = wn + ni * 16 + frow;
        out[(size_t)(m0 + row) * DOUT + n0 + col] = acc[mi][ni][j] + bias;
      }
    }
  }
}

// ---------------------------------------------------------------------------
extern "C" void kernel_launch(void* const* d_in, const int* in_sizes, int n_in,
                              void* d_out, int out_size, void* d_ws,
                              size_t ws_size, hipStream_t stream) {
  (void)in_sizes; (void)n_in; (void)out_size; (void)ws_size;
  const float* x  = (const float*)d_in[0];   // [4,4096,512]
  const float* ew = (const float*)d_in[1];   // [8,512,512]
  const float* eb = (const float*)d_in[2];   // [8,512]
  const float* mw = (const float*)d_in[3];   // [8,512]
  const float* mb = (const float*)d_in[4];   // [8]
  float* out = (float*)d_out;                // [4,4096,512]

  // workspace layout: xbf 16 MB | wbf 4 MB | coeffsT 0.5 MB  (~20.5 MB)
  u16* xbf = (u16*)d_ws;
  u16* wbf = (u16*)((char*)d_ws + (size_t)NTOK * DIN * 2);
  float* coeffsT =
      (float*)((char*)d_ws + (size_t)NTOK * DIN * 2 + (size_t)KE * DOUT * DIN * 2);

  hipLaunchKernelGGL(prologue_kernel, dim3(GATE_BLOCKS + WCONV_BLOCKS),
                     dim3(256), 0, stream, x, mw, mb, ew, xbf, wbf, coeffsT);
  hipLaunchKernelGGL(moe_gemm_kernel, dim3((NTOK / BM) * (DOUT / BN)), dim3(256),
                     0, stream, xbf, wbf, coeffsT, eb, out);
}

// Round 6
// 181.365 us; speedup vs baseline: 1.3619x; 1.3619x over previous
//
#include <hip/hip_runtime.h>
#include <stdint.h>

#define NTOK 16384   // B*S = 4*4096
#define DIN 512
#define DOUT 512
#define KE 8
#define BM 64
#define BN 128
#define BK 64

#define GATE_BLOCKS 2048           // 8 tokens/block
#define WCONV_BLOCKS 1024          // 2M elements / (256*8)

typedef unsigned short u16;
typedef u16 u16x8 __attribute__((ext_vector_type(8)));
typedef __bf16 bf16x8 __attribute__((ext_vector_type(8)));
typedef float f32x4 __attribute__((ext_vector_type(4)));

__device__ __forceinline__ u16 f2bf(float f) {
  union { float f; unsigned u; } v; v.f = f;
  unsigned r = v.u + 0x7FFFu + ((v.u >> 16) & 1u);   // RNE; inputs are finite
  return (u16)(r >> 16);
}

// async global->LDS, 16B per lane; LDS dest is wave-uniform base + lane*16
#define GLOAD_LDS16(gp, lp)                                              \
  __builtin_amdgcn_global_load_lds(                                     \
      (__attribute__((address_space(1))) void*)(gp),                    \
      (__attribute__((address_space(3))) void*)(lp), 16, 0, 0)

// ---------------------------------------------------------------------------
// Kernel 1 (merged prologue):
//  blocks [0, GATE_BLOCKS): gating softmax + x fp32->bf16 cast (8 tok/block)
//  blocks [GATE_BLOCKS, +WCONV_BLOCKS): expert-weight fp32->bf16 cast
// Coeffs written TRANSPOSED: coeffsT[e][tok]  (GEMM folds load float4).
// ---------------------------------------------------------------------------
__global__ __launch_bounds__(256) void prologue_kernel(
    const float* __restrict__ x, const float* __restrict__ mw,
    const float* __restrict__ mb, const float* __restrict__ ew,
    u16* __restrict__ xbf, u16* __restrict__ wbf, float* __restrict__ coeffsT) {
  const int tid = threadIdx.x;

  if (blockIdx.x >= GATE_BLOCKS) {
    // ---- weight cast: 8 elements/thread ----
    const size_t i =
        ((size_t)(blockIdx.x - GATE_BLOCKS) * 256 + tid) * 8;
    const float4 a = *(const float4*)&ew[i];
    const float4 b = *(const float4*)&ew[i + 4];
    u16x8 p;
    p[0] = f2bf(a.x); p[1] = f2bf(a.y); p[2] = f2bf(a.z); p[3] = f2bf(a.w);
    p[4] = f2bf(b.x); p[5] = f2bf(b.y); p[6] = f2bf(b.z); p[7] = f2bf(b.w);
    *(u16x8*)&wbf[i] = p;
    return;
  }

  // ---- gating + x cast ----
  __shared__ __align__(16) float mwS[KE * DIN];   // 16 KB
  const int wave = tid >> 6, lane = tid & 63;

#pragma unroll
  for (int i = 0; i < 4; ++i) {
    const int idx = (tid + i * 256) * 4;
    *(float4*)&mwS[idx] = *(const float4*)&mw[idx];
  }
  float mbr[KE];
#pragma unroll
  for (int k = 0; k < KE; ++k) mbr[k] = mb[k];
  __syncthreads();

#pragma unroll
  for (int t = 0; t < 2; ++t) {
    const int tok = blockIdx.x * 8 + wave * 2 + t;
    const float* xr = x + (size_t)tok * DIN + lane * 8;
    const float4 xa = *(const float4*)xr;
    const float4 xb = *(const float4*)(xr + 4);

    u16x8 p;
    p[0] = f2bf(xa.x); p[1] = f2bf(xa.y); p[2] = f2bf(xa.z); p[3] = f2bf(xa.w);
    p[4] = f2bf(xb.x); p[5] = f2bf(xb.y); p[6] = f2bf(xb.z); p[7] = f2bf(xb.w);
    *(u16x8*)(xbf + (size_t)tok * DIN + lane * 8) = p;

    float lg[KE];
#pragma unroll
    for (int k = 0; k < KE; ++k) {
      const float* wr = &mwS[k * DIN + lane * 8];
      const float4 w0 = *(const float4*)wr;
      const float4 w1 = *(const float4*)(wr + 4);
      lg[k] = xa.x * w0.x + xa.y * w0.y + xa.z * w0.z + xa.w * w0.w +
              xb.x * w1.x + xb.y * w1.y + xb.z * w1.z + xb.w * w1.w;
    }
#pragma unroll
    for (int off = 32; off; off >>= 1)
#pragma unroll
      for (int k = 0; k < KE; ++k) lg[k] += __shfl_xor(lg[k], off);

#pragma unroll
    for (int k = 0; k < KE; ++k) lg[k] += mbr[k];
    float mx = lg[0];
#pragma unroll
    for (int k = 1; k < KE; ++k) mx = fmaxf(mx, lg[k]);
    float s = 0.f;
#pragma unroll
    for (int k = 0; k < KE; ++k) { lg[k] = __expf(lg[k] - mx); s += lg[k]; }
    const float inv = 1.f / s;
    if (lane == 0) {
#pragma unroll
      for (int k = 0; k < KE; ++k) coeffsT[(size_t)k * NTOK + tok] = lg[k] * inv;
    }
  }
}

// ---------------------------------------------------------------------------
// Kernel 2: main MoE GEMM. BM=64 BN=128 BK=64 (R4's no-spill shape), but
// TWO K-tiles staged per barrier round into 2 LDS buffers: halves the
// barrier count and amortizes the vmcnt(0)-at-barrier drain (12 GLOADs'
// L2 latencies overlap) over 32 MFMA/wave instead of 16.
// LDS 48 KB -> 3 blocks/CU (matches R4's measured residency; R5 showed
// 1 block/CU kills it). NO prefetch across __syncthreads (compiler drains
// vmcnt(0) at barriers -- R5 lesson).
// - XCD swizzle (R2/R4): XCD b&7 owns 32 contiguous m-blocks.
// - XOR-swizzled LDS (R4: conflicts 5e5, R5: 0): slot s of row r holds
//   global chunk s^(r&7).
// - Bias fused into per-expert fold: acc += c*(part + beta_e[col]).
// ---------------------------------------------------------------------------
__global__ __launch_bounds__(256, 3) void moe_gemm_kernel(
    const u16* __restrict__ xbf, const u16* __restrict__ wbf,
    const float* __restrict__ coeffsT, const float* __restrict__ ebias,
    float* __restrict__ out) {
  __shared__ __align__(16) u16 As[2][BM * BK];   // 2 x 8 KB
  __shared__ __align__(16) u16 Bs[2][BN * BK];   // 2 x 16 KB

  const int tid = threadIdx.x;
  const int wave = tid >> 6, lane = tid & 63;

  // XCD swizzle: b&7 = xcd (round-robin dispatch), s = intra-XCD sequence.
  const int b = blockIdx.x;
  const int xcd = b & 7, s = b >> 3;
  const int m0 = (xcd * 32 + (s & 31)) * BM;
  const int n0 = (s >> 5) * BN;

  const int wm = (wave >> 1) * 32;   // wave's row offset: {0,32}
  const int wn = (wave & 1) * 64;    // wave's col offset: {0,64}

  // staging: each GLOAD covers 8 rows x 64 cols (1 KB). lane -> row lrow;
  // SOURCE col chunk XOR-swizzled: LDS slot s of row r = global chunk s^(r&7).
  const int lrow = lane >> 3;
  const int scol = ((lane & 7) ^ lrow) * 8;
  const u16* aBase = xbf + (size_t)(m0 + wave * 16 + lrow) * DIN + scol;
  const u16* bBase0 = wbf + (size_t)(n0 + wave * 32 + lrow) * DIN + scol;

  const int frow = lane & 15;
  const int fsel = lane >> 4;
  const int fxor = lane & 7;
  const int quad = lane >> 4;

  f32x4 acc[2][4] = {};

  for (int e = 0; e < KE; ++e) {
    f32x4 part[2][4] = {};
    const u16* aE = aBase;
    const u16* bE = bBase0 + (size_t)e * (DOUT * DIN);

    for (int h = 0; h < 4; ++h) {   // 4 rounds x 2 K-tiles = 512 K
      __syncthreads();   // previous round's LDS reads done
      // stage tiles 2h (buf 0) and 2h+1 (buf 1): 12 GLOADs back-to-back
#pragma unroll
      for (int buf = 0; buf < 2; ++buf) {
        const size_t koff = (size_t)(h * 2 + buf) * 64;
#pragma unroll
        for (int j = 0; j < 2; ++j)
          GLOAD_LDS16(aE + (size_t)(j * 8) * DIN + koff,
                      &As[buf][(wave * 2 + j) * 512]);
#pragma unroll
        for (int j = 0; j < 4; ++j)
          GLOAD_LDS16(bE + (size_t)(j * 8) * DIN + koff,
                      &Bs[buf][(wave * 4 + j) * 512]);
      }
      __syncthreads();   // drain -> both buffers valid

#pragma unroll
      for (int buf = 0; buf < 2; ++buf) {
#pragma unroll
        for (int ks = 0; ks < 2; ++ks) {
          const int slot = (ks * 4 + fsel) ^ fxor;   // rows mult of 8
          bf16x8 af[2], bfv[4];
#pragma unroll
          for (int mi = 0; mi < 2; ++mi)
            af[mi] = *(const bf16x8*)&As[buf][(wm + mi * 16 + frow) * BK + slot * 8];
#pragma unroll
          for (int ni = 0; ni < 4; ++ni)
            bfv[ni] = *(const bf16x8*)&Bs[buf][(wn + ni * 16 + frow) * BK + slot * 8];
#pragma unroll
          for (int mi = 0; mi < 2; ++mi)
#pragma unroll
            for (int ni = 0; ni < 4; ++ni)
              part[mi][ni] = __builtin_amdgcn_mfma_f32_16x16x32_bf16(
                  af[mi], bfv[ni], part[mi][ni], 0, 0, 0);
        }
      }
    }

    // fold expert into acc with fused bias: acc += c[row,e]*(part + beta[e,col])
    // C/D layout (m89/m91): col = lane&15, row = quad*4 + reg
    float bv[4];
#pragma unroll
    for (int ni = 0; ni < 4; ++ni)
      bv[ni] = ebias[e * DOUT + n0 + wn + ni * 16 + frow];
    const float* cT = coeffsT + (size_t)e * NTOK + m0;
#pragma unroll
    for (int mi = 0; mi < 2; ++mi) {
      const float4 c4 = *(const float4*)&cT[wm + mi * 16 + quad * 4];
#pragma unroll
      for (int ni = 0; ni < 4; ++ni) {
        acc[mi][ni][0] += c4.x * (part[mi][ni][0] + bv[ni]);
        acc[mi][ni][1] += c4.y * (part[mi][ni][1] + bv[ni]);
        acc[mi][ni][2] += c4.z * (part[mi][ni][2] + bv[ni]);
        acc[mi][ni][3] += c4.w * (part[mi][ni][3] + bv[ni]);
      }
    }
  }

  // epilogue: plain store (bias already folded)
#pragma unroll
  for (int mi = 0; mi < 2; ++mi) {
    const int rb = wm + mi * 16 + quad * 4;
#pragma unroll
    for (int j = 0; j < 4; ++j) {
      const int row = rb + j;
#pragma unroll
      for (int ni = 0; ni < 4; ++ni) {
        const int col = wn + ni * 16 + frow;
        out[(size_t)(m0 + row) * DOUT + n0 + col] = acc[mi][ni][j];
      }
    }
  }
}

// ---------------------------------------------------------------------------
extern "C" void kernel_launch(void* const* d_in, const int* in_sizes, int n_in,
                              void* d_out, int out_size, void* d_ws,
                              size_t ws_size, hipStream_t stream) {
  (void)in_sizes; (void)n_in; (void)out_size; (void)ws_size;
  const float* x  = (const float*)d_in[0];   // [4,4096,512]
  const float* ew = (const float*)d_in[1];   // [8,512,512]
  const float* eb = (const float*)d_in[2];   // [8,512]
  const float* mw = (const float*)d_in[3];   // [8,512]
  const float* mb = (const float*)d_in[4];   // [8]
  float* out = (float*)d_out;                // [4,4096,512]

  // workspace layout: xbf 16 MB | wbf 4 MB | coeffsT 0.5 MB  (~20.5 MB)
  u16* xbf = (u16*)d_ws;
  u16* wbf = (u16*)((char*)d_ws + (size_t)NTOK * DIN * 2);
  float* coeffsT =
      (float*)((char*)d_ws + (size_t)NTOK * DIN * 2 + (size_t)KE * DOUT * DIN * 2);

  hipLaunchKernelGGL(prologue_kernel, dim3(GATE_BLOCKS + WCONV_BLOCKS),
                     dim3(256), 0, stream, x, mw, mb, ew, xbf, wbf, coeffsT);
  hipLaunchKernelGGL(moe_gemm_kernel, dim3((NTOK / BM) * (DOUT / BN)), dim3(256),
                     0, stream, xbf, wbf, coeffsT, eb, out);
}